// Round 11
// baseline (173.967 us; speedup 1.0000x reference)
//
#include <hip/hip_runtime.h>

#define N_TRACES 128
#define TLEN 32
#define IN_DIM 64
#define HID 128
#define G4 512

typedef __attribute__((ext_vector_type(2))) float f32x2;

// ---------- helpers ----------

__device__ __forceinline__ float fast_sigmoid(float x) {
    return 1.0f / (1.0f + __expf(-x));
}
__device__ __forceinline__ float fast_tanh(float x) {
    return 1.0f - 2.0f / (__expf(2.0f * x) + 1.0f);
}
// sum across the 4 lanes of a quad, result in all 4 lanes
__device__ __forceinline__ float quad_reduce(float x) {
    x += __int_as_float(__builtin_amdgcn_update_dpp(
        0, __float_as_int(x), 0xB1 /*quad_perm [1,0,3,2]*/, 0xF, 0xF, true));
    x += __int_as_float(__builtin_amdgcn_update_dpp(
        0, __float_as_int(x), 0x4E /*quad_perm [2,3,0,1]*/, 0xF, 0xF, true));
    return x;
}

// load 4 gate rows {u+128i} of W[512][ld], k-slice [SW*s, SW*s+SW), as k-pairs.
// Values may be AGPR-parked (r2-r10: VGPR_Count=88); pin forbids re-fetch
// from global inside the loops (r9: 705 MB refetch disaster without residency).
template <int SW>
__device__ __forceinline__ void load_rows_pk(const float* __restrict__ W, int ld,
                                             int u, int s, f32x2 (&w)[4][SW / 2]) {
    #pragma unroll
    for (int i = 0; i < 4; ++i) {
        const float* wr = W + (size_t)(u + 128 * i) * ld + SW * s;
        #pragma unroll
        for (int j = 0; j < SW / 4; ++j) {
            float4 v = *(const float4*)(wr + 4 * j);
            w[i][2 * j + 0] = f32x2{v.x, v.y};
            w[i][2 * j + 1] = f32x2{v.z, v.w};
        }
    }
    #pragma unroll
    for (int i = 0; i < 4; ++i)
        #pragma unroll
        for (int j = 0; j < SW / 2; ++j)
            asm volatile("" : "+v"(w[i][j]));
}

// acc[i] (pair lanes: even-k in .x, odd-k in .y) += w[i] * h via v_pk_fma_f32:
// 2 MACs per instruction -> halves the per-step VALU issue (r10 finding:
// issue ~1900cyc/step at 128 scalar FMAs incl. AGPR-move tax).
template <int SW>
__device__ __forceinline__ void matvec_pk(const f32x2 (&w)[4][SW / 2],
                                          const float* hb, f32x2 (&acc)[4]) {
    #pragma unroll
    for (int j = 0; j < SW / 4; ++j) {
        float4 v = *(const float4*)(hb + 4 * j);
        f32x2 h01 = {v.x, v.y};
        f32x2 h23 = {v.z, v.w};
        #pragma unroll
        for (int i = 0; i < 4; ++i) {
            asm("v_pk_fma_f32 %0, %1, %2, %0"
                : "+v"(acc[i]) : "v"(w[i][2 * j + 0]), "v"(h01));
            asm("v_pk_fma_f32 %0, %1, %2, %0"
                : "+v"(acc[i]) : "v"(w[i][2 * j + 1]), "v"(h23));
        }
    }
}

// ---------- single fully-fused kernel (r10 committed structure + pk_fma) ----------
// 512 threads = 8 waves = 2 waves/SIMD. Thread (u=tid>>2, s=tid&3): gate rows
// {u+128i}, k-slice [32s,32s+32). hs padded p(k)=k+4*(k>>5): slice s at word
// 36s, conflict-free. No global ops inside loops (barrier drains vmcnt(0)).

__global__ __launch_bounds__(512) void lstm_all(
    const float* __restrict__ input, // [4096][64]
    const float* __restrict__ Wih0,  // [512][64]
    const float* __restrict__ Whh0,  // [512][128]
    const float* __restrict__ bih0,  // [512]
    const float* __restrict__ bhh0,  // [512]
    const float* __restrict__ Wih1,  // [512][128]
    const float* __restrict__ Whh1,  // [512][128]
    const float* __restrict__ bih1,  // [512]
    const float* __restrict__ bhh1,  // [512]
    const float* __restrict__ Wlin,  // [128]
    const float* __restrict__ blin,  // [1]
    float* __restrict__ y)           // [4096]
{
    const int trace = blockIdx.x;
    const int tid = threadIdx.x;
    const int u = tid >> 2;
    const int s = tid & 3;
    const int pu = u + 4 * (u >> 5); // padded word index for unit u

    __shared__ float xp[TLEN * G4];  // 64 KB: xproj0, later overwritten by xproj1
    __shared__ float hs[TLEN][140];  // 17.5 KB: x staging, then h1, then h2

    // ===== stage this trace's input (2048 floats) into the hs region =====
    {
        const float4* src = (const float4*)(input + (size_t)trace * TLEN * IN_DIM);
        ((float4*)&hs[0][0])[tid] = src[tid];
    }

    // ===== Phase A: xp[t] = Wih0 @ x(t) + b_ih0 + b_hh0 (t-parallel) =====
    {
        f32x2 w0[4][8];
        load_rows_pk<16>(Wih0, IN_DIM, u, s, w0);
        float bb[4];
        #pragma unroll
        for (int i = 0; i < 4; ++i) bb[i] = bih0[u + 128 * i] + bhh0[u + 128 * i];
        __syncthreads(); // x staged
        const float* xst = &hs[0][0];
        #pragma unroll 1
        for (int t = 0; t < TLEN; ++t) {
            f32x2 acc[4] = {f32x2{0.f, 0.f}, f32x2{0.f, 0.f}, f32x2{0.f, 0.f}, f32x2{0.f, 0.f}};
            matvec_pk<16>(w0, xst + t * IN_DIM + 16 * s, acc);
            float a[4];
            #pragma unroll
            for (int i = 0; i < 4; ++i) a[i] = quad_reduce(acc[i].x + acc[i].y);
            if (s == 0) {
                #pragma unroll
                for (int i = 0; i < 4; ++i) xp[t * G4 + 128 * i + u] = a[i] + bb[i];
            }
        }
    }
    __syncthreads(); // xp0 ready; hs region free for h1

    // ===== Phase B: layer-0 recurrence (h1 -> hs) =====
    {
        f32x2 w[4][16];
        load_rows_pk<32>(Whh0, HID, u, s, w);
        float cc = 0.f;
        // prime xg for t=0
        float xg0 = xp[u], xg1 = xp[128 + u], xg2 = xp[256 + u], xg3 = xp[384 + u];
        #pragma unroll 1
        for (int t = 0; t < TLEN; ++t) {
            f32x2 acc[4] = {f32x2{0.f, 0.f}, f32x2{0.f, 0.f}, f32x2{0.f, 0.f}, f32x2{0.f, 0.f}};
            if (t > 0) matvec_pk<32>(w, &hs[t - 1][36 * s], acc);
            float a[4];
            #pragma unroll
            for (int i = 0; i < 4; ++i) a[i] = quad_reduce(acc[i].x + acc[i].y);
            if (s == 0) {
                const float iv = fast_sigmoid(a[0] + xg0);
                const float fv = fast_sigmoid(a[1] + xg1);
                const float gv = fast_tanh(a[2] + xg2);
                const float ov = fast_sigmoid(a[3] + xg3);
                cc = fv * cc + iv * gv;
                hs[t][pu] = ov * fast_tanh(cc);
            }
            // prefetch next step's xg (xp stable all phase): latency hides in barrier
            if (t + 1 < TLEN) {
                xg0 = xp[(t + 1) * G4 + u];
                xg1 = xp[(t + 1) * G4 + 128 + u];
                xg2 = xp[(t + 1) * G4 + 256 + u];
                xg3 = xp[(t + 1) * G4 + 384 + u];
            }
            __syncthreads();
        }
    }

    // ===== Phase C: xp[t] = Wih1 @ h1(t) + b_ih1 + b_hh1 (t-parallel) =====
    {
        f32x2 w[4][16];
        load_rows_pk<32>(Wih1, HID, u, s, w);
        float bi[4];
        #pragma unroll
        for (int i = 0; i < 4; ++i) bi[i] = bih1[u + 128 * i] + bhh1[u + 128 * i];
        #pragma unroll 1
        for (int t = 0; t < TLEN; ++t) {
            f32x2 acc[4] = {f32x2{0.f, 0.f}, f32x2{0.f, 0.f}, f32x2{0.f, 0.f}, f32x2{0.f, 0.f}};
            matvec_pk<32>(w, &hs[t][36 * s], acc);
            float a[4];
            #pragma unroll
            for (int i = 0; i < 4; ++i) a[i] = quad_reduce(acc[i].x + acc[i].y);
            if (s == 0) {
                #pragma unroll
                for (int i = 0; i < 4; ++i) xp[t * G4 + 128 * i + u] = a[i] + bi[i];
            }
        }
    }
    __syncthreads(); // xp1 ready; h1 fully consumed

    // ===== Phase D: layer-1 recurrence (h2 overwrites hs) =====
    {
        f32x2 w[4][16];
        load_rows_pk<32>(Whh1, HID, u, s, w);
        float cc = 0.f;
        float xg0 = xp[u], xg1 = xp[128 + u], xg2 = xp[256 + u], xg3 = xp[384 + u];
        #pragma unroll 1
        for (int t = 0; t < TLEN; ++t) {
            f32x2 acc[4] = {f32x2{0.f, 0.f}, f32x2{0.f, 0.f}, f32x2{0.f, 0.f}, f32x2{0.f, 0.f}};
            if (t > 0) matvec_pk<32>(w, &hs[t - 1][36 * s], acc);
            float a[4];
            #pragma unroll
            for (int i = 0; i < 4; ++i) a[i] = quad_reduce(acc[i].x + acc[i].y);
            if (s == 0) {
                const float iv = fast_sigmoid(a[0] + xg0);
                const float fv = fast_sigmoid(a[1] + xg1);
                const float gv = fast_tanh(a[2] + xg2);
                const float ov = fast_sigmoid(a[3] + xg3);
                cc = fv * cc + iv * gv;
                hs[t][pu] = ov * fast_tanh(cc);
            }
            if (t + 1 < TLEN) {
                xg0 = xp[(t + 1) * G4 + u];
                xg1 = xp[(t + 1) * G4 + 128 + u];
                xg2 = xp[(t + 1) * G4 + 256 + u];
                xg3 = xp[(t + 1) * G4 + 384 + u];
            }
            __syncthreads();
        }
    }

    // ===== Phase E: y[trace*32+t] = dot(h2(t), W_lin) + b_lin =====
    if (tid < 128) {
        const int tq = tid >> 2;
        const int sq = tid & 3;
        float wl[32];
        #pragma unroll
        for (int j = 0; j < 8; ++j) {
            float4 v = *(const float4*)(Wlin + 32 * sq + 4 * j);
            wl[4 * j + 0] = v.x; wl[4 * j + 1] = v.y;
            wl[4 * j + 2] = v.z; wl[4 * j + 3] = v.w;
        }
        const float* hb = &hs[tq][36 * sq];
        float a = 0.f;
        #pragma unroll
        for (int j = 0; j < 8; ++j) {
            float4 v = *(const float4*)(hb + 4 * j);
            a = fmaf(v.x, wl[4 * j + 0], a);
            a = fmaf(v.y, wl[4 * j + 1], a);
            a = fmaf(v.z, wl[4 * j + 2], a);
            a = fmaf(v.w, wl[4 * j + 3], a);
        }
        a = quad_reduce(a);
        if (sq == 0) y[trace * TLEN + tq] = a + blin[0];
    }
}

// ---------- launch ----------

extern "C" void kernel_launch(void* const* d_in, const int* in_sizes, int n_in,
                              void* d_out, int out_size, void* d_ws, size_t ws_size,
                              hipStream_t stream) {
    const float* input = (const float*)d_in[0];  // [4096][64]
    const float* W_ih0 = (const float*)d_in[1];  // [512][64]
    const float* W_hh0 = (const float*)d_in[2];  // [512][128]
    const float* b_ih0 = (const float*)d_in[3];  // [512]
    const float* b_hh0 = (const float*)d_in[4];  // [512]
    const float* W_ih1 = (const float*)d_in[5];  // [512][128]
    const float* W_hh1 = (const float*)d_in[6];  // [512][128]
    const float* b_ih1 = (const float*)d_in[7];  // [512]
    const float* b_hh1 = (const float*)d_in[8];  // [512]
    const float* W_lin = (const float*)d_in[9];  // [1][128]
    const float* b_lin = (const float*)d_in[10]; // [1]
    float* out = (float*)d_out;                  // [4096]

    // single kernel, one WG per trace; d_ws unused
    lstm_all<<<N_TRACES, 512, 0, stream>>>(input, W_ih0, W_hh0, b_ih0, b_hh0,
                                           W_ih1, W_hh1, b_ih1, b_hh1,
                                           W_lin, b_lin, out);
}